// Round 8
// baseline (1032.183 us; speedup 1.0000x reference)
//
#include <hip/hip_runtime.h>
#include <stdint.h>

// BiLSTM-CRF forward on MI355X.
// R17 = R16 with the 20 ds_bpermute/lane/step (16 redistribute + 4 reunite
//       __shfl_xor(.,32)) replaced by v_permlane32_swap_b32 (VALU pipe, 1 op
//       each, lane-correspondent row swap -- bit-identical data movement).
//       LDS pipe/step/CU ~1600 -> ~700 cyc; two bpermute latency chains leave
//       the critical path. Everything else identical to R16 (1029 us, absmax 0).
typedef unsigned short u16;
typedef __attribute__((ext_vector_type(4))) float f32x4;
typedef __attribute__((ext_vector_type(8))) short short8;
typedef __attribute__((ext_vector_type(8))) int v8i;

#define OFF_BIAS   ((size_t)0)           // 2048*4
#define OFF_WFRAG  ((size_t)8192)        // 512 KB fp8 w_hh frags (K=128 grouping)
#define OFF_HHIST  ((size_t)1048576)     // [2][64][512][256] u16 = 32 MB
#define OFF_FEATS  ((size_t)34603008)    // 32768*9*4
#define OFF_XG     ((size_t)37748736)    // [2*8 grp][512 s][512 tid][16 u16] = 128 MB
#define OFF_XBF    ((size_t)171966464)   // [32768][256] u16 = 16 MB (gathered x, bf16)
#define OFF_WBF    ((size_t)188743680)   // [2][1024][256] u16 = 1 MB (w_ih, bf16)

__device__ __forceinline__ float bf2f(u16 h) {
  union { uint32_t u; float f; } v; v.u = ((uint32_t)h) << 16; return v.f;
}
__device__ __forceinline__ float bfh(uint32_t wrd, int hh) {
  return bf2f((u16)(wrd >> (16 * hh)));
}
__device__ __forceinline__ uint32_t cvtpk_bf16(float lo, float hi) {
  uint32_t r;
  asm("v_cvt_pk_bf16_f32 %0, %1, %2" : "=v"(r) : "v"(lo), "v"(hi));
  return r;
}
__device__ __forceinline__ uint32_t f2u(float f) {
  union { float f; uint32_t u; } v; v.f = f; return v.u;
}
__device__ __forceinline__ float u2f(uint32_t u) {
  union { uint32_t u; float f; } v; v.u = u; return v.f;
}
// permlane32_swap: given (a,b) returns lo = {a[0:31], b[0:31]},
// hi = {a[32:63], b[32:63]}, lane-correspondent (VALU pipe, no LDS).
__device__ __forceinline__ float pl32_lo(float a, float b) {
  auto pr = __builtin_amdgcn_permlane32_swap(f2u(a), f2u(b), false, false);
  return u2f(((const uint32_t*)&pr)[0]);
}
__device__ __forceinline__ float pl32_hi(float a, float b) {
  auto pr = __builtin_amdgcn_permlane32_swap(f2u(a), f2u(b), false, false);
  return u2f(((const uint32_t*)&pr)[1]);
}
__device__ __forceinline__ short8 pack8(f32x4 a, f32x4 b) {
  union { short8 s; uint32_t u[4]; } r;
  r.u[0] = cvtpk_bf16(a[0], a[1]);
  r.u[1] = cvtpk_bf16(a[2], a[3]);
  r.u[2] = cvtpk_bf16(b[0], b[1]);
  r.u[3] = cvtpk_bf16(b[2], b[3]);
  return r.s;
}

// ---- combined input-gate bias ----
__global__ void bias_kernel(const float* __restrict__ bihf, const float* __restrict__ bhhf,
                            const float* __restrict__ bihb, const float* __restrict__ bhhb,
                            float* __restrict__ bias) {
  int n = blockIdx.x * 256 + threadIdx.x;
  if (n < 1024) bias[n] = bihf[n] + bhhf[n];
  else          bias[n] = bihb[n - 1024] + bhhb[n - 1024];
}

// ---- one-time bf16 materialization: x = emb[sent] and w_ih, both as u16 ----
// Identical v_cvt_pk_bf16_f32 RNE as the old in-xg staging (bit-exact hoist).
__global__ void __launch_bounds__(256) pack_kernel(
    const int* __restrict__ sent, const float* __restrict__ emb,
    const float* __restrict__ wihf, const float* __restrict__ wihb,
    u16* __restrict__ xbf, u16* __restrict__ wbf)
{
  int gid = blockIdx.x * 256 + threadIdx.x;
  if (gid < 1048576) {                       // x: 32768 tokens x 256 cols / 8
    const int tok = gid >> 5;
    const int c8 = (gid & 31) * 8;
    const int t = sent[tok];
    const float* src = emb + (size_t)t * 256 + c8;
    f32x4 a0 = *(const f32x4*)(src);
    f32x4 a1 = *(const f32x4*)(src + 4);
    *(short8*)(xbf + (size_t)tok * 256 + c8) = pack8(a0, a1);
  } else if (gid < 1114112) {                // w_ih: 2 x 1024 x 256 / 8
    const int g2 = gid - 1048576;
    const int row = g2 >> 5;                 // 0..2047 = d*1024 + r
    const int c8 = (g2 & 31) * 8;
    const float* W = (row < 1024) ? wihf : wihb;
    const float* src = W + (size_t)(row & 1023) * 256 + c8;
    f32x4 a0 = *(const f32x4*)(src);
    f32x4 a1 = *(const f32x4*)(src + 4);
    *(short8*)(wbf + (size_t)row * 256 + c8) = pack8(a0, a1);
  }
}

// ---- w_hh -> fp8 e4m3 B-fragments (x16 scale), K-order permuted by pi ----
// pi: k = w*32 + n*2 + ubi  where unit u = w*32 + ubi*16 + n   (R3-verified)
// K=128 operand grouping: per (d,w,ubi,gate,p,l) contiguous 32 B, chunk
// kt = 4p + cc at byte offset cc*8 (pass cc covers k = 128p + 32cc + q*8 + j).
__global__ void wfrag_prep_kernel(const float* __restrict__ whhf,
                                  const float* __restrict__ whhb,
                                  uint8_t* __restrict__ wfrag) {
  int gid = blockIdx.x * 256 + threadIdx.x;   // 0..32767
  const int l    = gid & 63;
  const int kt   = (gid >> 6) & 7;
  const int gate = (gid >> 9) & 3;
  const int ubi  = (gid >> 11) & 1;
  const int w    = (gid >> 12) & 7;
  const int d    = (gid >> 15) & 1;
  const float* W = d ? whhb : whhf;
  const int n = l & 15, q = l >> 4;
  const int row = gate * 256 + w * 32 + ubi * 16 + n;
  uint32_t out[2] = {0u, 0u};
  #pragma unroll
  for (int jj = 0; jj < 4; ++jj) {
    const int k0 = kt * 32 + q * 8 + jj * 2;
    const int k1 = k0 + 1;
    const int u0 = (k0 >> 5) * 32 + (k0 & 1) * 16 + ((k0 & 31) >> 1);
    const int u1 = (k1 >> 5) * 32 + (k1 & 1) * 16 + ((k1 & 31) >> 1);
    const float f0 = W[(size_t)row * 256 + u0] * 16.0f;
    const float f1 = W[(size_t)row * 256 + u1] * 16.0f;
    const int pk = __builtin_amdgcn_cvt_pk_fp8_f32(f0, f1, 0, false);
    out[jj >> 1] |= (uint32_t)(pk & 0xffff) << (16 * (jj & 1));
  }
  const int p = kt >> 2, cc = kt & 3;
  const size_t addr =
      ((((size_t)((d * 8 + w) * 2 + ubi) * 4 + gate) * 2 + p) * 64 + l) * 32 + (size_t)cc * 8;
  *(uint2*)(wfrag + addr) = make_uint2(out[0], out[1]);
}

// ---- xg = x_bf16 @ w_ih^T + bias, coalesced epilogue in lstm lane order ----
// xg layout: [d][g8(8)][s(512)][tid(512)][16 u16], tid slice = [gate(4)][r(4)]
// for lstm lane (w = tid>>6, q = (ubi<<1)|qh, n): batch m = qh*4 + r.
// Epilogue folds exp2-domain scale: i,f,o -> *(-log2e); g -> *(+2*log2e).
// Staging is pure short8 copies from the pre-packed bf16 buffers.
__global__ void __launch_bounds__(256) xg_gemm_kernel(
    const u16* __restrict__ xbf, const u16* __restrict__ wbf,
    const float* __restrict__ bias, u16* __restrict__ xgf)
{
  extern __shared__ char smem[];
  u16*   Al    = (u16*)smem;             // [128][136]
  u16*   Bl    = (u16*)(smem + 34816);   // [128][136]
  float* biasl = (float*)(smem + 69632); // [128]

  const int tid = threadIdx.x;
  const int d  = blockIdx.x >> 3, u0 = (blockIdx.x & 7) * 32;
  const int g  = blockIdx.y >> 6, qb = (blockIdx.y >> 4) & 3, s0 = (blockIdx.y & 15) * 32;

  if (tid < 128)
    biasl[tid] = bias[d * 1024 + (tid >> 5) * 256 + u0 + (tid & 31)];
  __syncthreads();

  f32x4 acc[4][4];
  #pragma unroll
  for (int i = 0; i < 4; ++i)
    #pragma unroll
    for (int j = 0; j < 4; ++j) acc[i][j] = (f32x4){0.f, 0.f, 0.f, 0.f};

  const int wv = tid >> 6, l = tid & 63;
  const int mh = (wv >> 1) * 64, nh = (wv & 1) * 64;
  const int fr = l & 15, fq = l >> 4;
  const int rr = tid >> 1, c0 = (tid & 1) * 64;

  // A row rr -> x row p = (g*16 + qb*4 + (rr&3))*512 + s0 + (rr>>2)
  const int xrow = (g * 16 + qb * 4 + (rr & 3)) * 512 + s0 + (rr >> 2);
  // B row rr -> w row = d*1024 + (rr>>5)*256 + u0 + (rr&31)
  const int wrow = d * 1024 + (rr >> 5) * 256 + u0 + (rr & 31);

  for (int kc = 0; kc < 2; ++kc) {
    const int k0 = kc * 128;
    const u16* as = xbf + (size_t)xrow * 256 + k0 + c0;
    const u16* bs = wbf + (size_t)wrow * 256 + k0 + c0;
    u16* adst = Al + rr * 136 + c0;
    u16* bdst = Bl + rr * 136 + c0;
    #pragma unroll
    for (int gdx = 0; gdx < 8; ++gdx) {
      *(short8*)(adst + gdx * 8) = *(const short8*)(as + gdx * 8);
      *(short8*)(bdst + gdx * 8) = *(const short8*)(bs + gdx * 8);
    }
    __syncthreads();
    #pragma unroll
    for (int ks = 0; ks < 4; ++ks) {
      short8 af[4], bfr[4];
      #pragma unroll
      for (int i = 0; i < 4; ++i)
        af[i] = *(const short8*)(Al + (mh + i * 16 + fr) * 136 + ks * 32 + fq * 8);
      #pragma unroll
      for (int j = 0; j < 4; ++j)
        bfr[j] = *(const short8*)(Bl + (nh + j * 16 + fr) * 136 + ks * 32 + fq * 8);
      #pragma unroll
      for (int i = 0; i < 4; ++i)
        #pragma unroll
        for (int j = 0; j < 4; ++j)
          acc[i][j] = __builtin_amdgcn_mfma_f32_16x16x32_bf16(af[i], bfr[j], acc[i][j], 0, 0, 0);
    }
    __syncthreads();
  }

  // epilogue: per (i,nsub) one 16-B store = gates {g0,g0+1} x r0..3 for ubi=nsub.
  const float LOG2E = 1.4426950408889634f;
  const int g0 = nh >> 5;                 // gates {g0, g0+1}, g0 in {0,2}
  const float sA = (g0 == 2) ? (2.0f * LOG2E) : (-LOG2E);  // gate 2 = g (tanh form)
  const int mh4 = mh >> 2;
  const int g8 = g * 2 + (qb >> 1);
  const int qh = qb & 1;
  u16* xbase = xgf + (size_t)(d * 8 + g8) * 4194304;   // 512*512*16 u16
  #pragma unroll
  for (int i = 0; i < 4; ++i) {
    const int s = s0 + mh4 + i * 4 + fq;
    #pragma unroll
    for (int nsub = 0; nsub < 2; ++nsub) {
      const int j0 = nsub, j1 = nsub + 2;
      const int cA = nh + j0 * 16 + fr, cB = nh + j1 * 16 + fr;
      const int tid2 = (u0 >> 5) * 64 + ((nsub << 1) | qh) * 16 + fr;
      float vA[4], vB[4];
      #pragma unroll
      for (int r = 0; r < 4; ++r) {
        vA[r] = (acc[i][j0][r] + biasl[cA]) * sA;          // gate g0
        vB[r] = (acc[i][j1][r] + biasl[cB]) * (-LOG2E);    // gate g0+1
      }
      union { short8 s8; uint32_t u[4]; } sv;
      sv.u[0] = cvtpk_bf16(vA[0], vA[1]);
      sv.u[1] = cvtpk_bf16(vA[2], vA[3]);
      sv.u[2] = cvtpk_bf16(vB[0], vB[1]);
      sv.u[3] = cvtpk_bf16(vB[2], vB[3]);
      *(short8*)(xbase + (size_t)s * 8192 + tid2 * 16 + g0 * 4) = sv.s8;
    }
  }
}

// ---- one LSTM timestep (8-batch WG); CB reads h_{t-1}, PW receives h_t ----
// Lane (w, q, n): post-redistribution owns cells (ubi = q>>1, m = (q&1)*4 + r),
// r = 0..3, unit = w*32 + (q>>1)*16 + n. Redistribution/reunite now via
// v_permlane32_swap (VALU) instead of ds_bpermute (LDS) -- same data movement.
template<int CB, int PW>
__device__ __forceinline__ void lstm_step(
    int T, int d, int l, int q, int n, int w,
    const v8i (&wvr)[2][4][2], float (&cst)[4],
    uint4& X0, uint4& X1,
    uint8_t* hx, const u16* xsl, u16* hhb)
{
  const int t_eff = d ? (511 - T) : T;
  const int qh = q & 1;

  // top-of-step prefetch for T+2 (whole step to land; no barrier drain)
  int tn = T + 2; if (tn > 511) tn = 511;
  const int sn = d ? (511 - tn) : tn;
  const uint4* pf = (const uint4*)(xsl + (size_t)sn * 8192);
  const uint4 P0 = pf[0], P1 = pf[1];

  // A fragments from hx[CB]: lane -> m = l&15 (rows 8..15 are zero), k-chunks.
  const uint8_t* hr = hx + CB * 4224 + (l & 15) * 264 + q * 8;
  const int2 b0 = *(const int2*)(hr +   0);
  const int2 b1 = *(const int2*)(hr +  32);
  const int2 b2 = *(const int2*)(hr +  64);
  const int2 b3 = *(const int2*)(hr +  96);
  const int2 b4 = *(const int2*)(hr + 128);
  const int2 b5 = *(const int2*)(hr + 160);
  const int2 b6 = *(const int2*)(hr + 192);
  const int2 b7 = *(const int2*)(hr + 224);
  const v8i A0 = (v8i){b0.x, b0.y, b1.x, b1.y, b2.x, b2.y, b3.x, b3.y};
  const v8i A1 = (v8i){b4.x, b4.y, b5.x, b5.y, b6.x, b6.y, b7.x, b7.y};

  // MFMA: 2 unit-blocks x 4 gates x 2 K=128 instrs (scales = 1.0)
  f32x4 acc[2][4];
  #pragma unroll
  for (int ubi = 0; ubi < 2; ++ubi)
    #pragma unroll
    for (int gate = 0; gate < 4; ++gate) {
      f32x4 a = (f32x4){0.f, 0.f, 0.f, 0.f};
      a = __builtin_amdgcn_mfma_scale_f32_16x16x128_f8f6f4(
              A0, wvr[ubi][gate][0], a, 0, 0, 0, 0x7f7f7f7f, 0, 0x7f7f7f7f);
      a = __builtin_amdgcn_mfma_scale_f32_16x16x128_f8f6f4(
              A1, wvr[ubi][gate][1], a, 0, 0, 0, 0x7f7f7f7f, 0, 0x7f7f7f7f);
      acc[ubi][gate] = a;
    }

  // redistribute via permlane32_swap: lo-result lanes 0-31 = acc[0] (own valid
  // rows 0..7), lanes 32-63 = acc[1] from lane l-32 (valid ubi=1 rows 0..7).
  // Bit-identical to R13's shfl_xor(acc[1],32) + (q<2) select, zero LDS ops.
  f32x4 accs[4];
  #pragma unroll
  for (int gate = 0; gate < 4; ++gate)
    #pragma unroll
    for (int r = 0; r < 4; ++r)
      accs[gate][r] = pl32_lo(acc[0][gate][r], acc[1][gate][r]);

  // gate math in exp2 domain; cells m = qh*4 + r.
  // xg pre-scaled: i,f,o by -log2e; g by +2*log2e (incl. bias).
  const float Sm = -0.0056355275f;   // -log2e/256
  const float Sg =  0.0112710550f;   // +2*log2e/256
  const float K2 =  2.8853900818f;   // 2*log2e
  float hval[4];
  #pragma unroll
  for (int r = 0; r < 4; ++r) {
    const uint32_t wi = (r < 2) ? X0.x : X0.y;
    const uint32_t wf = (r < 2) ? X0.z : X0.w;
    const uint32_t wg = (r < 2) ? X1.x : X1.y;
    const uint32_t wo = (r < 2) ? X1.z : X1.w;
    const int hp = r & 1;
    const float argi = fmaf(accs[0][r], Sm, bfh(wi, hp));  // = -iv*log2e
    const float argf = fmaf(accs[1][r], Sm, bfh(wf, hp));  // = -fv*log2e
    const float argg = fmaf(accs[2][r], Sg, bfh(wg, hp));  // = +2g*log2e
    const float argo = fmaf(accs[3][r], Sm, bfh(wo, hp));  // = -ov*log2e
    const float Ei = __builtin_amdgcn_exp2f(argi);
    const float Ef = __builtin_amdgcn_exp2f(argf);
    const float Eg = __builtin_amdgcn_exp2f(argg);
    const float Eo = __builtin_amdgcn_exp2f(argo);
    const float pf_ = 1.0f + Ef, pi_ = 1.0f + Ei, pg_ = 1.0f + Eg;
    const float P  = pi_ * pg_;
    const float rD = __builtin_amdgcn_rcpf(P * pf_);
    // c = sf*c + si*tg = [c*P + (Eg-1)*pf_] / (P*pf_)
    const float num = fmaf(cst[r], P, fmaf(Eg, pf_, -pf_));
    const float c   = num * rD;
    cst[r] = c;
    const float E2 = __builtin_amdgcn_exp2f(c * K2);
    const float rQ = __builtin_amdgcn_rcpf((1.0f + E2) * (1.0f + Eo));
    // h = so*tanh(c) = (E2-1) / ((1+E2)(1+Eo))
    hval[r] = fmaf(E2, rQ, -rQ);
  }

  // reunite via permlane32_swap: hi-result lanes 0-31 = hval from lane l+32.
  // Then lanes q<2 publish u16 fp8 pairs at pi-order byte k = w*32 + 2n + ubi
  // (2 writers/dword, measured free).
  float ho[4];
  #pragma unroll
  for (int r = 0; r < 4; ++r) ho[r] = pl32_hi(hval[r], hval[r]);
  if (q < 2) {
    uint8_t* hw = hx + PW * 4224 + w * 32 + 2 * n;
    #pragma unroll
    for (int r = 0; r < 4; ++r) {
      const int pk = __builtin_amdgcn_cvt_pk_fp8_f32(hval[r] * 16.0f,
                                                     ho[r] * 16.0f, 0, false);
      *(u16*)(hw + (q * 4 + r) * 264) = (u16)(pk & 0xffff);
    }
  }

  // soft barrier: wait only LDS ops (publish) -- X prefetch + hist stores stay
  // in flight across it.
  asm volatile("s_waitcnt lgkmcnt(0)" ::: "memory");
  __builtin_amdgcn_s_barrier();
  __builtin_amdgcn_sched_barrier(0);

  // bf16 history AFTER the barrier -- drains under next step's MFMAs.
  // Each lane stores its own 4 cells (batch m = qh*4+r, unit w*32+(q>>1)*16+n).
  {
    u16* hhs = hhb + (size_t)t_eff * 256;
    const uint32_t pb01 = cvtpk_bf16(hval[0], hval[1]);
    const uint32_t pb23 = cvtpk_bf16(hval[2], hval[3]);
    hhs[(size_t)(qh * 4 + 0) * 131072] = (u16)(pb01 & 0xffffu);
    hhs[(size_t)(qh * 4 + 1) * 131072] = (u16)(pb01 >> 16);
    hhs[(size_t)(qh * 4 + 2) * 131072] = (u16)(pb23 & 0xffffu);
    hhs[(size_t)(qh * 4 + 3) * 131072] = (u16)(pb23 >> 16);
  }

  // commit prefetch (X regs now free)
  X0 = P0; X1 = P1;
}

// ---- self-contained BiLSTM: 16 WGs = dir(2) x batch-group(8 of 8) ----
// 512 threads = 8 waves; wave w owns units [32w,32w+32) x 4 gates in regs/AGPRs.
__global__ void __launch_bounds__(512, 2) lstm_kernel(
    const u16* __restrict__ xgf, const uint8_t* __restrict__ wfrag,
    u16* __restrict__ hhist)
{
  __shared__ uint8_t hx[2 * 16 * 264];   // fp8 h double-buffer, stride 264

  const int tid = threadIdx.x;
  const int bid = blockIdx.x;            // 0..15
  const int d = bid >> 3, g8 = bid & 7;
  const int w = tid >> 6, l = tid & 63;
  const int n = l & 15, q = l >> 4;

  // register/AGPR-resident fp8 weight fragments (128 regs), K=128 grouping
  v8i wvr[2][4][2];
  {
    const uint8_t* wb = wfrag + (size_t)(d * 8 + w) * 32768;
    #pragma unroll
    for (int ubi = 0; ubi < 2; ++ubi)
      #pragma unroll
      for (int gate = 0; gate < 4; ++gate)
        #pragma unroll
        for (int p = 0; p < 2; ++p) {
          const uint8_t* src = wb + ((size_t)(((ubi * 4 + gate) * 2 + p) * 64 + l)) * 32;
          const uint4 lo = *(const uint4*)(src);
          const uint4 hi = *(const uint4*)(src + 16);
          wvr[ubi][gate][p] = (v8i){(int)lo.x, (int)lo.y, (int)lo.z, (int)lo.w,
                                    (int)hi.x, (int)hi.y, (int)hi.z, (int)hi.w};
        }
  }

  for (int i = tid; i < 2112; i += 512) ((uint32_t*)hx)[i] = 0u;  // h_{-1}=0; rows 8..15 stay 0

  const u16* xsl = xgf + (size_t)(d * 8 + g8) * 4194304 + (size_t)tid * 16;
  float cst[4] = {};
  u16* hhb = hhist + ((size_t)(d * 64 + g8 * 8) * 512) * 256 + (w * 32 + (q >> 1) * 16 + n);

  // preload xg for t=0 (X) and t=1 (Y)
  uint4 X0, X1, Y0, Y1;
  {
    const uint4* p0 = (const uint4*)(xsl + (size_t)(d ? 511 : 0) * 8192);
    X0 = p0[0]; X1 = p0[1];
    const uint4* p1 = (const uint4*)(xsl + (size_t)(d ? 510 : 1) * 8192);
    Y0 = p1[0]; Y1 = p1[1];
  }
  __syncthreads();

  for (int tt = 0; tt < 512; tt += 2) {
    lstm_step<0, 1>(tt,     d, l, q, n, w, wvr, cst, X0, X1, hx, xsl, hhb);
    lstm_step<1, 0>(tt + 1, d, l, q, n, w, wvr, cst, Y0, Y1, hx, xsl, hhb);
  }
}

// ---- feats = [hf|hb] @ w_out^T + b_out ----
__global__ void __launch_bounds__(256) proj_kernel(
    const u16* __restrict__ hhist, const float* __restrict__ w_out,
    const float* __restrict__ b_out, float* __restrict__ feats)
{
  __shared__ float wsm[9 * 512];
  __shared__ float bsm[9];
  const int tid = threadIdx.x;
  for (int i = tid; i < 4608; i += 256) wsm[i] = w_out[i];
  if (tid < 9) bsm[tid] = b_out[tid];
  __syncthreads();

  const int wv = tid >> 6, l = tid & 63;
  const int gw = blockIdx.x * 4 + wv;
  const int jb = l * 8;
  const int dd = jb >> 8;
  const int jloc = jb & 255;

  for (int qq = 0; qq < 8; ++qq) {
    const int pos = gw * 8 + qq;
    const int b = pos >> 9, s = pos & 511;
    const u16* hp = hhist + ((size_t)(dd * 64 + b) * 512 + s) * 256 + jloc;
    short8 hv8 = *(const short8*)hp;
    float hf[8];
    #pragma unroll
    for (int j = 0; j < 8; ++j) hf[j] = bf2f((u16)hv8[j]);
    float pt[9];
    #pragma unroll
    for (int tg2 = 0; tg2 < 9; ++tg2) {
      const float* wr = wsm + tg2 * 512 + jb;
      float a = 0.f;
      #pragma unroll
      for (int j = 0; j < 8; ++j) a = fmaf(hf[j], wr[j], a);
      pt[tg2] = a;
    }
    #pragma unroll
    for (int tg2 = 0; tg2 < 9; ++tg2)
      #pragma unroll
      for (int off = 32; off; off >>= 1)
        pt[tg2] += __shfl_xor(pt[tg2], off, 64);
    if (l == 0) {
      float* fo = feats + (size_t)pos * 9;
      #pragma unroll
      for (int tg2 = 0; tg2 < 9; ++tg2) fo[tg2] = pt[tg2] + bsm[tg2];
    }
  }
}

// ---- CRF NLL ----
__global__ void __launch_bounds__(64) crf_kernel(
    const float* __restrict__ feats, const int* __restrict__ tags,
    const float* __restrict__ strans, const float* __restrict__ etrans,
    const float* __restrict__ trans, float* out)
{
  __shared__ float em[512 * 9];
  __shared__ float tr[81];
  __shared__ int   tg[512];
  const int b = blockIdx.x, l = threadIdx.x;
  const float* fb = feats + (size_t)b * 512 * 9;
  for (int i = l; i < 4608; i += 64) em[i] = fb[i];
  for (int i = l; i < 512; i += 64) tg[i] = tags[b * 512 + i];
  if (l < 81) tr[l] = trans[l];
  __syncthreads();

  float sc = 0.f;
  for (int s = 1 + l; s < 512; s += 64)
    sc += tr[tg[s - 1] * 9 + tg[s]] + em[s * 9 + tg[s]];
  #pragma unroll
  for (int off = 32; off; off >>= 1) sc += __shfl_xor(sc, off, 64);
  const float score = sc + strans[tg[0]] + em[tg[0]] + etrans[tg[511]];

  const int jj = (l < 9) ? l : 0;
  float al = (l < 9) ? (strans[l] + em[l]) : -1e30f;
  for (int t = 1; t < 512; ++t) {
    float ai[9];
    #pragma unroll
    for (int i = 0; i < 9; ++i) ai[i] = __shfl(al, i, 64);
    float m = ai[0];
    #pragma unroll
    for (int i = 1; i < 9; ++i) m = fmaxf(m, ai[i]);
    float ssum = 0.f;
    #pragma unroll
    for (int i = 0; i < 9; ++i) ssum += __expf(ai[i] + tr[i * 9 + jj] - m);
    al = em[t * 9 + jj] + m + __logf(ssum);
  }
  float v = (l < 9) ? (al + etrans[l]) : -3.0e38f;
  float m2 = v;
  #pragma unroll
  for (int off = 32; off; off >>= 1) m2 = fmaxf(m2, __shfl_xor(m2, off, 64));
  float ex = (l < 9) ? __expf(v - m2) : 0.f;
  #pragma unroll
  for (int off = 32; off; off >>= 1) ex += __shfl_xor(ex, off, 64);
  const float logZ = m2 + __logf(ex);
  if (l == 0) atomicAdd(out, -(score - logZ) * (1.0f / 64.0f));
}

extern "C" void kernel_launch(void* const* d_in, const int* in_sizes, int n_in,
                              void* d_out, int out_size, void* d_ws, size_t ws_size,
                              hipStream_t stream) {
  (void)in_sizes; (void)n_in; (void)out_size; (void)ws_size;
  const int*   sent = (const int*)d_in[0];
  const int*   tags = (const int*)d_in[1];
  const float* emb  = (const float*)d_in[3];
  const float* wihf = (const float*)d_in[4];
  const float* whhf = (const float*)d_in[5];
  const float* bihf = (const float*)d_in[6];
  const float* bhhf = (const float*)d_in[7];
  const float* wihb = (const float*)d_in[8];
  const float* whhb = (const float*)d_in[9];
  const float* bihb = (const float*)d_in[10];
  const float* bhhb = (const float*)d_in[11];
  const float* wout = (const float*)d_in[12];
  const float* bout = (const float*)d_in[13];
  const float* strn = (const float*)d_in[14];
  const float* etrn = (const float*)d_in[15];
  const float* trn  = (const float*)d_in[16];

  char* ws = (char*)d_ws;
  float*   biasb = (float*)(ws + OFF_BIAS);
  uint8_t* wfrag = (uint8_t*)(ws + OFF_WFRAG);
  u16*     hhist = (u16*)(ws + OFF_HHIST);
  float*   feats = (float*)(ws + OFF_FEATS);
  u16*     xgf   = (u16*)(ws + OFF_XG);
  u16*     xbf   = (u16*)(ws + OFF_XBF);
  u16*     wbf   = (u16*)(ws + OFF_WBF);
  float*   out   = (float*)d_out;

  hipMemsetAsync(d_out, 0, sizeof(float), stream);

  hipFuncSetAttribute(reinterpret_cast<const void*>(xg_gemm_kernel),
                      hipFuncAttributeMaxDynamicSharedMemorySize, 70656);

  bias_kernel<<<8, 256, 0, stream>>>(bihf, bhhf, bihb, bhhb, biasb);
  pack_kernel<<<4352, 256, 0, stream>>>(sent, emb, wihf, wihb, xbf, wbf);
  wfrag_prep_kernel<<<128, 256, 0, stream>>>(whhf, whhb, wfrag);
  xg_gemm_kernel<<<dim3(16, 256), 256, 70656, stream>>>(xbf, wbf, biasb, xgf);
  lstm_kernel<<<16, 512, 0, stream>>>(xgf, wfrag, hhist);
  proj_kernel<<<1024, 256, 0, stream>>>(hhist, wout, bout, feats);
  crf_kernel<<<64, 64, 0, stream>>>(feats, tags, strn, etrn, trn, out);
}

// Round 9
// 946.472 us; speedup vs baseline: 1.0906x; 1.0906x over previous
//
#include <hip/hip_runtime.h>
#include <stdint.h>

// BiLSTM-CRF forward on MI355X.
// R18: lstm 16 WGs x 8 batches -> 32 WGs x 4 batches (2 dir x 16 groups).
//      Convoy model (R17-validated): step = MFMA(1105) + VALU/trans(1460) +
//      LDS(~500) serial phases. This halves the trans/VALU phase: 2 cells/lane.
//      Cell distribution: permlane32_swap (R17-verified) splits ubi across
//      half-waves; NEW permlane16_swap broadcasts even 16-lane rows to odd rows
//      (VALU pipe) to split r-pairs across q parity. Publish 2 u16/lane (proven
//      2-writers/dword), hist 2 stores, xg slice 16B/lane contiguous
//      [d][g16][s][tid][8 u16] = [gate(4)][j(2)]. MFMA/A-reads/wfrag unchanged.
typedef unsigned short u16;
typedef __attribute__((ext_vector_type(4))) float f32x4;
typedef __attribute__((ext_vector_type(8))) short short8;
typedef __attribute__((ext_vector_type(8))) int v8i;

#define OFF_BIAS   ((size_t)0)           // 2048*4
#define OFF_WFRAG  ((size_t)8192)        // 512 KB fp8 w_hh frags (K=128 grouping)
#define OFF_HHIST  ((size_t)1048576)     // [2][64][512][256] u16 = 32 MB
#define OFF_FEATS  ((size_t)34603008)    // 32768*9*4
#define OFF_XG     ((size_t)37748736)    // [2*16 grp][512 s][512 tid][8 u16] = 128 MB
#define OFF_XBF    ((size_t)171966464)   // [32768][256] u16 = 16 MB (gathered x, bf16)
#define OFF_WBF    ((size_t)188743680)   // [2][1024][256] u16 = 1 MB (w_ih, bf16)

__device__ __forceinline__ float bf2f(u16 h) {
  union { uint32_t u; float f; } v; v.u = ((uint32_t)h) << 16; return v.f;
}
__device__ __forceinline__ float bfh(uint32_t wrd, int hh) {
  return bf2f((u16)(wrd >> (16 * hh)));
}
__device__ __forceinline__ uint32_t cvtpk_bf16(float lo, float hi) {
  uint32_t r;
  asm("v_cvt_pk_bf16_f32 %0, %1, %2" : "=v"(r) : "v"(lo), "v"(hi));
  return r;
}
__device__ __forceinline__ uint32_t f2u(float f) {
  union { float f; uint32_t u; } v; v.f = f; return v.u;
}
__device__ __forceinline__ float u2f(uint32_t u) {
  union { uint32_t u; float f; } v; v.u = u; return v.f;
}
// permlane32_swap: result0 = {a[0:31] in lanes 0-31, b[0:31] in lanes 32-63},
// lane-correspondent (VALU pipe). Verified on HW in R17 (absmax 0).
__device__ __forceinline__ float pl32_lo(float a, float b) {
  auto pr = __builtin_amdgcn_permlane32_swap(f2u(a), f2u(b), false, false);
  return u2f(((const uint32_t*)&pr)[0]);
}
__device__ __forceinline__ float pl32_hi(float a, float b) {
  auto pr = __builtin_amdgcn_permlane32_swap(f2u(a), f2u(b), false, false);
  return u2f(((const uint32_t*)&pr)[1]);
}
// permlane16_swap(x,x) result0: even 16-lane rows keep x, odd rows receive the
// even row below (lane 16k+16+i <- lane 16k+i). VALU pipe.
__device__ __forceinline__ float pl16_bcast(float x) {
#if __has_builtin(__builtin_amdgcn_permlane16_swap)
  auto pr = __builtin_amdgcn_permlane16_swap(f2u(x), f2u(x), false, false);
  return u2f(((const uint32_t*)&pr)[0]);
#else
  uint32_t a = f2u(x), b = f2u(x);
  asm("v_permlane16_swap_b32 %0, %1" : "+v"(a), "+v"(b));
  return u2f(a);
#endif
}
__device__ __forceinline__ short8 pack8(f32x4 a, f32x4 b) {
  union { short8 s; uint32_t u[4]; } r;
  r.u[0] = cvtpk_bf16(a[0], a[1]);
  r.u[1] = cvtpk_bf16(a[2], a[3]);
  r.u[2] = cvtpk_bf16(b[0], b[1]);
  r.u[3] = cvtpk_bf16(b[2], b[3]);
  return r.s;
}

// ---- combined input-gate bias ----
__global__ void bias_kernel(const float* __restrict__ bihf, const float* __restrict__ bhhf,
                            const float* __restrict__ bihb, const float* __restrict__ bhhb,
                            float* __restrict__ bias) {
  int n = blockIdx.x * 256 + threadIdx.x;
  if (n < 1024) bias[n] = bihf[n] + bhhf[n];
  else          bias[n] = bihb[n - 1024] + bhhb[n - 1024];
}

// ---- one-time bf16 materialization: x = emb[sent] and w_ih, both as u16 ----
__global__ void __launch_bounds__(256) pack_kernel(
    const int* __restrict__ sent, const float* __restrict__ emb,
    const float* __restrict__ wihf, const float* __restrict__ wihb,
    u16* __restrict__ xbf, u16* __restrict__ wbf)
{
  int gid = blockIdx.x * 256 + threadIdx.x;
  if (gid < 1048576) {                       // x: 32768 tokens x 256 cols / 8
    const int tok = gid >> 5;
    const int c8 = (gid & 31) * 8;
    const int t = sent[tok];
    const float* src = emb + (size_t)t * 256 + c8;
    f32x4 a0 = *(const f32x4*)(src);
    f32x4 a1 = *(const f32x4*)(src + 4);
    *(short8*)(xbf + (size_t)tok * 256 + c8) = pack8(a0, a1);
  } else if (gid < 1114112) {                // w_ih: 2 x 1024 x 256 / 8
    const int g2 = gid - 1048576;
    const int row = g2 >> 5;                 // 0..2047 = d*1024 + r
    const int c8 = (g2 & 31) * 8;
    const float* W = (row < 1024) ? wihf : wihb;
    const float* src = W + (size_t)(row & 1023) * 256 + c8;
    f32x4 a0 = *(const f32x4*)(src);
    f32x4 a1 = *(const f32x4*)(src + 4);
    *(short8*)(wbf + (size_t)row * 256 + c8) = pack8(a0, a1);
  }
}

// ---- w_hh -> fp8 e4m3 B-fragments (x16 scale), K-order permuted by pi ----
__global__ void wfrag_prep_kernel(const float* __restrict__ whhf,
                                  const float* __restrict__ whhb,
                                  uint8_t* __restrict__ wfrag) {
  int gid = blockIdx.x * 256 + threadIdx.x;   // 0..32767
  const int l    = gid & 63;
  const int kt   = (gid >> 6) & 7;
  const int gate = (gid >> 9) & 3;
  const int ubi  = (gid >> 11) & 1;
  const int w    = (gid >> 12) & 7;
  const int d    = (gid >> 15) & 1;
  const float* W = d ? whhb : whhf;
  const int n = l & 15, q = l >> 4;
  const int row = gate * 256 + w * 32 + ubi * 16 + n;
  uint32_t out[2] = {0u, 0u};
  #pragma unroll
  for (int jj = 0; jj < 4; ++jj) {
    const int k0 = kt * 32 + q * 8 + jj * 2;
    const int k1 = k0 + 1;
    const int u0 = (k0 >> 5) * 32 + (k0 & 1) * 16 + ((k0 & 31) >> 1);
    const int u1 = (k1 >> 5) * 32 + (k1 & 1) * 16 + ((k1 & 31) >> 1);
    const float f0 = W[(size_t)row * 256 + u0] * 16.0f;
    const float f1 = W[(size_t)row * 256 + u1] * 16.0f;
    const int pk = __builtin_amdgcn_cvt_pk_fp8_f32(f0, f1, 0, false);
    out[jj >> 1] |= (uint32_t)(pk & 0xffff) << (16 * (jj & 1));
  }
  const int p = kt >> 2, cc = kt & 3;
  const size_t addr =
      ((((size_t)((d * 8 + w) * 2 + ubi) * 4 + gate) * 2 + p) * 64 + l) * 32 + (size_t)cc * 8;
  *(uint2*)(wfrag + addr) = make_uint2(out[0], out[1]);
}

// ---- xg = x_bf16 @ w_ih^T + bias, epilogue in NEW lstm lane order ----
// xg layout: [d][g16(16)][s(512)][tid(512)][8 u16], slice = [gate(4)][j(2)]
// for lstm lane tid = w*64 + q*16 + n: cells m = (q&1)*2 + j of batch group g16.
// Scale fold: i,f,o -> *(-log2e); g -> *(+2*log2e).
__global__ void __launch_bounds__(256) xg_gemm_kernel(
    const u16* __restrict__ xbf, const u16* __restrict__ wbf,
    const float* __restrict__ bias, u16* __restrict__ xgf)
{
  extern __shared__ char smem[];
  u16*   Al    = (u16*)smem;             // [128][136]
  u16*   Bl    = (u16*)(smem + 34816);   // [128][136]
  float* biasl = (float*)(smem + 69632); // [128]

  const int tid = threadIdx.x;
  const int d  = blockIdx.x >> 3, u0 = (blockIdx.x & 7) * 32;
  const int g  = blockIdx.y >> 6, qb = (blockIdx.y >> 4) & 3, s0 = (blockIdx.y & 15) * 32;

  if (tid < 128)
    biasl[tid] = bias[d * 1024 + (tid >> 5) * 256 + u0 + (tid & 31)];
  __syncthreads();

  f32x4 acc[4][4];
  #pragma unroll
  for (int i = 0; i < 4; ++i)
    #pragma unroll
    for (int j = 0; j < 4; ++j) acc[i][j] = (f32x4){0.f, 0.f, 0.f, 0.f};

  const int wv = tid >> 6, l = tid & 63;
  const int mh = (wv >> 1) * 64, nh = (wv & 1) * 64;
  const int fr = l & 15, fq = l >> 4;
  const int rr = tid >> 1, c0 = (tid & 1) * 64;

  const int xrow = (g * 16 + qb * 4 + (rr & 3)) * 512 + s0 + (rr >> 2);
  const int wrow = d * 1024 + (rr >> 5) * 256 + u0 + (rr & 31);

  for (int kc = 0; kc < 2; ++kc) {
    const int k0 = kc * 128;
    const u16* as = xbf + (size_t)xrow * 256 + k0 + c0;
    const u16* bs = wbf + (size_t)wrow * 256 + k0 + c0;
    u16* adst = Al + rr * 136 + c0;
    u16* bdst = Bl + rr * 136 + c0;
    #pragma unroll
    for (int gdx = 0; gdx < 8; ++gdx) {
      *(short8*)(adst + gdx * 8) = *(const short8*)(as + gdx * 8);
      *(short8*)(bdst + gdx * 8) = *(const short8*)(bs + gdx * 8);
    }
    __syncthreads();
    #pragma unroll
    for (int ks = 0; ks < 4; ++ks) {
      short8 af[4], bfr[4];
      #pragma unroll
      for (int i = 0; i < 4; ++i)
        af[i] = *(const short8*)(Al + (mh + i * 16 + fr) * 136 + ks * 32 + fq * 8);
      #pragma unroll
      for (int j = 0; j < 4; ++j)
        bfr[j] = *(const short8*)(Bl + (nh + j * 16 + fr) * 136 + ks * 32 + fq * 8);
      #pragma unroll
      for (int i = 0; i < 4; ++i)
        #pragma unroll
        for (int j = 0; j < 4; ++j)
          acc[i][j] = __builtin_amdgcn_mfma_f32_16x16x32_bf16(af[i], bfr[j], acc[i][j], 0, 0, 0);
    }
    __syncthreads();
  }

  // epilogue: per (i, nsub=ubi, p=parity) one 8-B store = 4 u16 at slice
  // offset g0*2: {gate g0 j0,j1, gate g0+1 j0,j1} for cells m = p*2 + j.
  const float LOG2E = 1.4426950408889634f;
  const int g0 = nh >> 5;                 // gates {g0, g0+1}, g0 in {0,2}
  const float sA = (g0 == 2) ? (2.0f * LOG2E) : (-LOG2E);  // gate 2 = g (tanh form)
  const int mh4 = mh >> 2;
  const int g16 = g * 4 + qb;             // batch group of 4
  u16* xbase = xgf + (size_t)(d * 16 + g16) * 2097152;   // 512*512*8 u16
  #pragma unroll
  for (int i = 0; i < 4; ++i) {
    const int s = s0 + mh4 + i * 4 + fq;
    #pragma unroll
    for (int nsub = 0; nsub < 2; ++nsub) {
      const int cA = nh + nsub * 16 + fr, cB = nh + (nsub + 2) * 16 + fr;
      float vA[4], vB[4];
      #pragma unroll
      for (int r = 0; r < 4; ++r) {
        vA[r] = (acc[i][nsub][r] + biasl[cA]) * sA;            // gate g0
        vB[r] = (acc[i][nsub + 2][r] + biasl[cB]) * (-LOG2E);  // gate g0+1
      }
      #pragma unroll
      for (int p = 0; p < 2; ++p) {
        uint2 sv;
        sv.x = cvtpk_bf16(vA[p * 2], vA[p * 2 + 1]);
        sv.y = cvtpk_bf16(vB[p * 2], vB[p * 2 + 1]);
        const int tid2 = (u0 >> 5) * 64 + ((nsub << 1) | p) * 16 + fr;
        *(uint2*)(xbase + (size_t)s * 4096 + tid2 * 8 + g0 * 2) = sv;
      }
    }
  }
}

// ---- one LSTM timestep (4-batch WG); CB reads h_{t-1}, PW receives h_t ----
// Lane (w, q, n) owns cells (ubi = q>>1, m = (q&1)*2 + j), j = 0,1,
// unit = w*32 + (q>>1)*16 + n. ubi-split via permlane32_swap (R17-verified),
// r-pair split via permlane16_swap even->odd row broadcast (VALU pipe).
template<int CB, int PW>
__device__ __forceinline__ void lstm_step(
    int T, int d, int l, int q, int n, int w,
    const v8i (&wvr)[2][4][2], float (&cst)[2],
    uint4& X0,
    uint8_t* hx, const u16* xsl, u16* hhb)
{
  const int t_eff = d ? (511 - T) : T;

  // top-of-step prefetch for T+2 (whole step to land; no barrier drain)
  int tn = T + 2; if (tn > 511) tn = 511;
  const int sn = d ? (511 - tn) : tn;
  const uint4 P0 = *(const uint4*)(xsl + (size_t)sn * 4096);

  // A fragments from hx[CB]: lane -> m = l&15 (rows 4..15 are zero), k-chunks.
  const uint8_t* hr = hx + CB * 4224 + (l & 15) * 264 + q * 8;
  const int2 b0 = *(const int2*)(hr +   0);
  const int2 b1 = *(const int2*)(hr +  32);
  const int2 b2 = *(const int2*)(hr +  64);
  const int2 b3 = *(const int2*)(hr +  96);
  const int2 b4 = *(const int2*)(hr + 128);
  const int2 b5 = *(const int2*)(hr + 160);
  const int2 b6 = *(const int2*)(hr + 192);
  const int2 b7 = *(const int2*)(hr + 224);
  const v8i A0 = (v8i){b0.x, b0.y, b1.x, b1.y, b2.x, b2.y, b3.x, b3.y};
  const v8i A1 = (v8i){b4.x, b4.y, b5.x, b5.y, b6.x, b6.y, b7.x, b7.y};

  // MFMA: 2 unit-blocks x 4 gates x 2 K=128 instrs (scales = 1.0)
  f32x4 acc[2][4];
  #pragma unroll
  for (int ubi = 0; ubi < 2; ++ubi)
    #pragma unroll
    for (int gate = 0; gate < 4; ++gate) {
      f32x4 a = (f32x4){0.f, 0.f, 0.f, 0.f};
      a = __builtin_amdgcn_mfma_scale_f32_16x16x128_f8f6f4(
              A0, wvr[ubi][gate][0], a, 0, 0, 0, 0x7f7f7f7f, 0, 0x7f7f7f7f);
      a = __builtin_amdgcn_mfma_scale_f32_16x16x128_f8f6f4(
              A1, wvr[ubi][gate][1], a, 0, 0, 0, 0x7f7f7f7f, 0, 0x7f7f7f7f);
      acc[ubi][gate] = a;
    }

  // stage 1 (ubi split, lanes q<2 get acc[0], q>=2 get acc[1] rows 0..3):
  f32x4 accs[4];
  #pragma unroll
  for (int gate = 0; gate < 4; ++gate)
    #pragma unroll
    for (int r = 0; r < 4; ++r)
      accs[gate][r] = pl32_lo(acc[0][gate][r], acc[1][gate][r]);

  // stage 2 (r-pair split, odd-q lanes receive r=2+j from even-q partner):
  float a2[4][2];
  #pragma unroll
  for (int gate = 0; gate < 4; ++gate)
    #pragma unroll
    for (int j = 0; j < 2; ++j) {
      const float t1 = pl16_bcast(accs[gate][2 + j]);
      a2[gate][j] = (q & 1) ? t1 : accs[gate][j];
    }

  // gate math in exp2 domain; cells m = (q&1)*2 + j.
  // xg pre-scaled: i,f,o by -log2e; g by +2*log2e (incl. bias).
  const float Sm = -0.0056355275f;   // -log2e/256
  const float Sg =  0.0112710550f;   // +2*log2e/256
  const float K2 =  2.8853900818f;   // 2*log2e
  float hval[2];
  #pragma unroll
  for (int j = 0; j < 2; ++j) {
    const float argi = fmaf(a2[0][j], Sm, bfh(X0.x, j));  // = -iv*log2e
    const float argf = fmaf(a2[1][j], Sm, bfh(X0.y, j));  // = -fv*log2e
    const float argg = fmaf(a2[2][j], Sg, bfh(X0.z, j));  // = +2g*log2e
    const float argo = fmaf(a2[3][j], Sm, bfh(X0.w, j));  // = -ov*log2e
    const float Ei = __builtin_amdgcn_exp2f(argi);
    const float Ef = __builtin_amdgcn_exp2f(argf);
    const float Eg = __builtin_amdgcn_exp2f(argg);
    const float Eo = __builtin_amdgcn_exp2f(argo);
    const float pf_ = 1.0f + Ef, pi_ = 1.0f + Ei, pg_ = 1.0f + Eg;
    const float P  = pi_ * pg_;
    const float rD = __builtin_amdgcn_rcpf(P * pf_);
    // c = sf*c + si*tg = [c*P + (Eg-1)*pf_] / (P*pf_)
    const float num = fmaf(cst[j], P, fmaf(Eg, pf_, -pf_));
    const float c   = num * rD;
    cst[j] = c;
    const float E2 = __builtin_amdgcn_exp2f(c * K2);
    const float rQ = __builtin_amdgcn_rcpf((1.0f + E2) * (1.0f + Eo));
    // h = so*tanh(c) = (E2-1) / ((1+E2)(1+Eo))
    hval[j] = fmaf(E2, rQ, -rQ);
  }

  // reunite via permlane32_swap: lanes q<2 get partner's (q+2) ubi=1 hval.
  const float ho0 = pl32_hi(hval[0], hval[0]);
  const float ho1 = pl32_hi(hval[1], hval[1]);
  if (q < 2) {
    uint8_t* hw = hx + PW * 4224 + w * 32 + 2 * n;
    const int m0 = (q & 1) * 2;
    const int pk0 = __builtin_amdgcn_cvt_pk_fp8_f32(hval[0] * 16.0f, ho0 * 16.0f, 0, false);
    const int pk1 = __builtin_amdgcn_cvt_pk_fp8_f32(hval[1] * 16.0f, ho1 * 16.0f, 0, false);
    *(u16*)(hw + (m0)     * 264) = (u16)(pk0 & 0xffff);
    *(u16*)(hw + (m0 + 1) * 264) = (u16)(pk1 & 0xffff);
  }

  // soft barrier: wait only LDS ops (publish) -- prefetch + hist stores stay
  // in flight across it.
  asm volatile("s_waitcnt lgkmcnt(0)" ::: "memory");
  __builtin_amdgcn_s_barrier();
  __builtin_amdgcn_sched_barrier(0);

  // bf16 history AFTER the barrier -- drains under next step's MFMAs.
  // Each lane stores its own 2 cells (batch m = (q&1)*2+j).
  {
    u16* hhs = hhb + (size_t)t_eff * 256;
    const uint32_t pb = cvtpk_bf16(hval[0], hval[1]);
    const int m0 = (q & 1) * 2;
    hhs[(size_t)(m0)     * 131072] = (u16)(pb & 0xffffu);
    hhs[(size_t)(m0 + 1) * 131072] = (u16)(pb >> 16);
  }

  // commit prefetch
  X0 = P0;
}

// ---- self-contained BiLSTM: 32 WGs = dir(2) x batch-group(16 of 4) ----
// 512 threads = 8 waves; wave w owns units [32w,32w+32) x 4 gates in regs/AGPRs.
__global__ void __launch_bounds__(512, 2) lstm_kernel(
    const u16* __restrict__ xgf, const uint8_t* __restrict__ wfrag,
    u16* __restrict__ hhist)
{
  __shared__ uint8_t hx[2 * 16 * 264];   // fp8 h double-buffer, stride 264

  const int tid = threadIdx.x;
  const int bid = blockIdx.x;            // 0..31
  const int d = bid >> 4, g16 = bid & 15;
  const int w = tid >> 6, l = tid & 63;
  const int n = l & 15, q = l >> 4;

  // register/AGPR-resident fp8 weight fragments (128 regs), K=128 grouping
  v8i wvr[2][4][2];
  {
    const uint8_t* wb = wfrag + (size_t)(d * 8 + w) * 32768;
    #pragma unroll
    for (int ubi = 0; ubi < 2; ++ubi)
      #pragma unroll
      for (int gate = 0; gate < 4; ++gate)
        #pragma unroll
        for (int p = 0; p < 2; ++p) {
          const uint8_t* src = wb + ((size_t)(((ubi * 4 + gate) * 2 + p) * 64 + l)) * 32;
          const uint4 lo = *(const uint4*)(src);
          const uint4 hi = *(const uint4*)(src + 16);
          wvr[ubi][gate][p] = (v8i){(int)lo.x, (int)lo.y, (int)lo.z, (int)lo.w,
                                    (int)hi.x, (int)hi.y, (int)hi.z, (int)hi.w};
        }
  }

  for (int i = tid; i < 2112; i += 512) ((uint32_t*)hx)[i] = 0u;  // h_{-1}=0; rows 4..15 stay 0

  const u16* xsl = xgf + (size_t)(d * 16 + g16) * 2097152 + (size_t)tid * 8;
  float cst[2] = {};
  u16* hhb = hhist + ((size_t)(d * 64 + g16 * 4) * 512) * 256 + (w * 32 + (q >> 1) * 16 + n);

  // preload xg for t=0 (X) and t=1 (Y)
  uint4 X0, Y0;
  X0 = *(const uint4*)(xsl + (size_t)(d ? 511 : 0) * 4096);
  Y0 = *(const uint4*)(xsl + (size_t)(d ? 510 : 1) * 4096);
  __syncthreads();

  for (int tt = 0; tt < 512; tt += 2) {
    lstm_step<0, 1>(tt,     d, l, q, n, w, wvr, cst, X0, hx, xsl, hhb);
    lstm_step<1, 0>(tt + 1, d, l, q, n, w, wvr, cst, Y0, hx, xsl, hhb);
  }
}

// ---- feats = [hf|hb] @ w_out^T + b_out ----
__global__ void __launch_bounds__(256) proj_kernel(
    const u16* __restrict__ hhist, const float* __restrict__ w_out,
    const float* __restrict__ b_out, float* __restrict__ feats)
{
  __shared__ float wsm[9 * 512];
  __shared__ float bsm[9];
  const int tid = threadIdx.x;
  for (int i = tid; i < 4608; i += 256) wsm[i] = w_out[i];
  if (tid < 9) bsm[tid] = b_out[tid];
  __syncthreads();

  const int wv = tid >> 6, l = tid & 63;
  const int gw = blockIdx.x * 4 + wv;
  const int jb = l * 8;
  const int dd = jb >> 8;
  const int jloc = jb & 255;

  for (int qq = 0; qq < 8; ++qq) {
    const int pos = gw * 8 + qq;
    const int b = pos >> 9, s = pos & 511;
    const u16* hp = hhist + ((size_t)(dd * 64 + b) * 512 + s) * 256 + jloc;
    short8 hv8 = *(const short8*)hp;
    float hf[8];
    #pragma unroll
    for (int j = 0; j < 8; ++j) hf[j] = bf2f((u16)hv8[j]);
    float pt[9];
    #pragma unroll
    for (int tg2 = 0; tg2 < 9; ++tg2) {
      const float* wr = wsm + tg2 * 512 + jb;
      float a = 0.f;
      #pragma unroll
      for (int j = 0; j < 8; ++j) a = fmaf(hf[j], wr[j], a);
      pt[tg2] = a;
    }
    #pragma unroll
    for (int tg2 = 0; tg2 < 9; ++tg2)
      #pragma unroll
      for (int off = 32; off; off >>= 1)
        pt[tg2] += __shfl_xor(pt[tg2], off, 64);
    if (l == 0) {
      float* fo = feats + (size_t)pos * 9;
      #pragma unroll
      for (int tg2 = 0; tg2 < 9; ++tg2) fo[tg2] = pt[tg2] + bsm[tg2];
    }
  }
}

// ---- CRF NLL ----
__global__ void __launch_bounds__(64) crf_kernel(
    const float* __restrict__ feats, const int* __restrict__ tags,
    const float* __restrict__ strans, const float* __restrict__ etrans,
    const float* __restrict__ trans, float* out)
{
  __shared__ float em[512 * 9];
  __shared__ float tr[81];
  __shared__ int   tg[512];
  const int b = blockIdx.x, l = threadIdx.x;
  const float* fb = feats + (size_t)b * 512 * 9;
  for (int i = l; i < 4608; i += 64) em[i] = fb[i];
  for (int i = l; i < 512; i += 64) tg[i] = tags[b * 512 + i];
  if (l < 81) tr[l] = trans[l];
  __syncthreads();

  float sc = 0.f;
  for (int s = 1 + l; s < 512; s += 64)
    sc += tr[tg[s - 1] * 9 + tg[s]] + em[s * 9 + tg[s]];
  #pragma unroll
  for (int off = 32; off; off >>= 1) sc += __shfl_xor(sc, off, 64);
  const float score = sc + strans[tg[0]] + em[tg[0]] + etrans[tg[511]];

  const int jj = (l < 9) ? l : 0;
  float al = (l < 9) ? (strans[l] + em[l]) : -1e30f;
  for (int t = 1; t < 512; ++t) {
    float ai[9];
    #pragma unroll
    for (int i = 0; i < 9; ++i) ai[i] = __shfl(al, i, 64);
    float m = ai[0];
    #pragma unroll
    for (int i = 1; i < 9; ++i) m = fmaxf(m, ai[i]);
    float ssum = 0.f;
    #pragma unroll
    for (int i = 0; i < 9; ++i) ssum += __expf(ai[i] + tr[i * 9 + jj] - m);
    al = em[t * 9 + jj] + m + __logf(ssum);
  }
  float v = (l < 9) ? (al + etrans[l]) : -3.0e38f;
  float m2 = v;
  #pragma unroll
  for (int off = 32; off; off >>= 1) m2 = fmaxf(m2, __shfl_xor(m2, off, 64));
  float ex = (l < 9) ? __expf(v - m2) : 0.f;
  #pragma unroll
  for (int off = 32; off; off >>= 1) ex += __shfl_xor(ex, off, 64);
  const float logZ = m2 + __logf(ex);
  if (l == 0) atomicAdd(out, -(score - logZ) * (1.0f / 64.0f));
}

extern "C" void kernel_launch(void* const* d_in, const int* in_sizes, int n_in,
                              void* d_out, int out_size, void* d_ws, size_t ws_size,
                              hipStream_t stream) {
  (void)in_sizes; (void)n_in; (void)out_size; (void)ws_size;
  const int*   sent = (const int*)d_in[0];
  const int*   tags = (const int*)d_in[1];
  const float* emb  = (const float*)d_in[3];
  const float* wihf = (const float*)d_in[4];
  const float* whhf = (const float*)d_in[5];
  const float* bihf = (const float*)d_in[6];
  const float* bhhf = (const float*)d_in[7];
  const float* wihb = (const float*)d_in[8];
  const float* whhb = (const float*)d_in[9];
  const float* bihb = (const float*)d_in[10];
  const float* bhhb = (const float*)d_in[11];
  const float* wout = (const float*)d_in[12];
  const float* bout = (const float*)d_in[13];
  const float* strn = (const float*)d_in[14];
  const float* etrn = (const float*)d_in[15];
  const float* trn  = (const float*)d_in[16];

  char* ws = (char*)d_ws;
  float*   biasb = (float*)(ws + OFF_BIAS);
  uint8_t* wfrag = (uint8_t*)(ws + OFF_WFRAG);
  u16*     hhist = (u16*)(ws + OFF_HHIST);
  float*   feats = (float*)(ws + OFF_FEATS);
  u16*     xgf   = (u16*)(ws + OFF_XG);
  u16*     xbf   = (u16*)(ws + OFF_XBF);
  u16*     wbf   = (u16*)(ws + OFF_WBF);
  float*   out   = (float*)d_out;

  hipMemsetAsync(d_out, 0, sizeof(float), stream);

  hipFuncSetAttribute(reinterpret_cast<const void*>(xg_gemm_kernel),
                      hipFuncAttributeMaxDynamicSharedMemorySize, 70656);

  bias_kernel<<<8, 256, 0, stream>>>(bihf, bhhf, bihb, bhhb, biasb);
  pack_kernel<<<4352, 256, 0, stream>>>(sent, emb, wihf, wihb, xbf, wbf);
  wfrag_prep_kernel<<<128, 256, 0, stream>>>(whhf, whhb, wfrag);
  xg_gemm_kernel<<<dim3(16, 256), 256, 70656, stream>>>(xbf, wbf, biasb, xgf);
  lstm_kernel<<<32, 512, 0, stream>>>(xgf, wfrag, hhist);
  proj_kernel<<<1024, 256, 0, stream>>>(hhist, wout, bout, feats);
  crf_kernel<<<64, 64, 0, stream>>>(feats, tags, strn, etrn, trn, out);
}